// Round 2
// baseline (14512.292 us; speedup 1.0000x reference)
//
#include <hip/hip_runtime.h>

#define KM 29

__device__ __forceinline__ float silu_f(float x){ return x / (1.0f + __expf(-x)); }

__device__ __forceinline__ float wave_reduce_sum(float v){
  #pragma unroll
  for (int s = 1; s < 64; s <<= 1) v += __shfl_xor(v, s);
  return v;
}

__device__ __forceinline__ constexpr int LOFc(int k){
  return (k==0)?0 : (k<4)?1 : (k<9)?2 : (k<14)?3 : (k<19)?4 : (k<24)?5 : 6;
}

// ---------------- CSR build ----------------
__global__ void k_count(const int* __restrict__ EI, int* __restrict__ cnt, int E){
  int e = blockIdx.x*256 + threadIdx.x;
  if (e < E) atomicAdd(&cnt[EI[E+e]], 1);
}

__global__ __launch_bounds__(1024) void k_scan(int* __restrict__ cnt, int* __restrict__ rowptr, int N){
  __shared__ int ts[1024];
  int t = threadIdx.x;
  int base = t*8;
  int loc[8]; int sum = 0;
  #pragma unroll
  for (int u = 0; u < 8; u++){ int idx = base+u; int v = (idx < N) ? cnt[idx] : 0; loc[u] = sum; sum += v; }
  ts[t] = sum; __syncthreads();
  for (int off = 1; off < 1024; off <<= 1){
    int v = (t >= off) ? ts[t-off] : 0;
    __syncthreads();
    ts[t] += v;
    __syncthreads();
  }
  int excl = ts[t] - sum;
  #pragma unroll
  for (int u = 0; u < 8; u++){
    int idx = base+u;
    if (idx < N){ int r = excl + loc[u]; rowptr[idx] = r; cnt[idx] = r; }
  }
  if (t == 1023) rowptr[N] = ts[1023];
}

__global__ void k_fill(const int* __restrict__ EI, int* __restrict__ cur, int* __restrict__ order, int E){
  int e = blockIdx.x*256 + threadIdx.x;
  if (e < E){ int pos = atomicAdd(&cur[EI[E+e]], 1); order[pos] = e; }
}

__global__ void k_sort(const int* __restrict__ rowptr, int* __restrict__ order, int N){
  int n = blockIdx.x*256 + threadIdx.x;
  if (n >= N) return;
  int rp = rowptr[n], re = rowptr[n+1];
  for (int a = rp+1; a < re; a++){
    int key = order[a]; int b = a-1;
    while (b >= rp && order[b] > key){ order[b+1] = order[b]; b--; }
    order[b+1] = key;
  }
}

// ---------------- edge radial embedding ----------------
// wave per edge; 32-wide gaussian band (err ~ e^-32); fused 2-layer MLPs
__global__ __launch_bounds__(256) void k_edge_embed(
    const float* __restrict__ ed, const float* __restrict__ We0, const float* __restrict__ be0,
    const float* __restrict__ We1, const float* __restrict__ be1,
    const float* __restrict__ Wr0, const float* __restrict__ Wr1, const float* __restrict__ Wrl,
    float* __restrict__ h2b, float* __restrict__ radl, float* __restrict__ envb, int E)
{
  __shared__ float sb[4][640];
  const int wid = threadIdx.x >> 6, lane = threadIdx.x & 63;
  const int e = blockIdx.x*4 + wid;
  if (e >= E) return;
  const float d = ed[e];
  if (lane == 0){
    float xx = d * (1.0f/12.0f);
    float x2 = xx*xx, x4 = x2*x2, x5 = x4*xx;
    float env = 1.0f - 21.0f*x5 + 35.0f*x5*xx - 15.0f*x5*x2;
    envb[e] = (xx < 1.0f) ? env : 0.0f;
  }
  const float DLT = 12.0f/599.0f;
  const float CO  = -0.5f/((2.0f*DLT)*(2.0f*DLT));
  int jc = (int)(d/DLT + 0.5f);
  int j0 = jc - 16; if (j0 < 0) j0 = 0; if (j0 > 600-32) j0 = 600-32;
  float diff = d - (float)(j0+lane)*DLT;   // lanes >=32 unused
  float gval = __expf(CO*diff*diff);
  float p[10];
  #pragma unroll
  for (int u = 0; u < 10; u++) p[u] = 0.f;
  const int c2 = 2*lane;
  for (int jj = 0; jj < 32; jj++){
    float gj = __shfl(gval, jj);
    int row = j0 + jj;
    const float2 w0 = *(const float2*)(We0 + row*128 + c2);
    p[0] += gj*w0.x; p[1] += gj*w0.y;
    #pragma unroll
    for (int i = 0; i < 4; i++){
      const float2 wr = *(const float2*)(Wr0 + ((size_t)i*600 + row)*128 + c2);
      p[2+2*i] += gj*wr.x; p[3+2*i] += gj*wr.y;
    }
  }
  sb[wid][c2]   = silu_f(p[0] + be0[c2]);
  sb[wid][c2+1] = silu_f(p[1] + be0[c2+1]);
  #pragma unroll
  for (int i = 0; i < 4; i++){
    sb[wid][128 + 128*i + c2]   = silu_f(p[2+2*i]);
    sb[wid][128 + 128*i + c2+1] = silu_f(p[3+2*i]);
  }
  // h2 = silu(h @ We1 + be1)
  float a0 = 0.f, a1 = 0.f;
  for (int c = 0; c < 128; c++){
    float hv = sb[wid][c];
    const float2 w = *(const float2*)(We1 + c*128 + c2);
    a0 += hv*w.x; a1 += hv*w.y;
  }
  a0 = silu_f(a0 + be1[c2]); a1 = silu_f(a1 + be1[c2+1]);
  h2b[(size_t)e*128 + c2]     = a0;
  h2b[(size_t)e*128 + c2 + 1] = a1;
  // rad_i = silu(silu(p_i) @ Wr1[i]); radl = rad @ Wrl[i]
  #pragma unroll
  for (int i = 0; i < 4; i++){
    float r0 = 0.f, r1 = 0.f;
    const float* W1 = Wr1 + (size_t)i*128*128;
    for (int c = 0; c < 128; c++){
      float rv = sb[wid][128 + 128*i + c];
      const float2 w = *(const float2*)(W1 + c*128 + c2);
      r0 += rv*w.x; r1 += rv*w.y;
    }
    r0 = silu_f(r0); r1 = silu_f(r1);
    const float* Wl = Wrl + (size_t)i*128*7;
    float pl[7];
    #pragma unroll
    for (int l = 0; l < 7; l++) pl[l] = r0*Wl[c2*7+l] + r1*Wl[(c2+1)*7+l];
    #pragma unroll
    for (int l = 0; l < 7; l++) pl[l] = wave_reduce_sum(pl[l]);
    if (lane == 0){
      #pragma unroll
      for (int l = 0; l < 7; l++) radl[(size_t)e*28 + i*7 + l] = pl[l];
    }
  }
}

// ---------------- x init: emb + degree-projected sum ----------------
__global__ __launch_bounds__(256) void k_init_x(
    const int* __restrict__ Z, const float* __restrict__ emb, const float* __restrict__ Weproj,
    const float* __restrict__ h2b, const int* __restrict__ rowptr, const int* __restrict__ order,
    float* __restrict__ X)
{
  __shared__ float h2s[128];
  __shared__ float er[128];
  int n = blockIdx.x, t = threadIdx.x;
  int rp = rowptr[n], deg = rowptr[n+1] - rp;
  if (t < 128){
    float acc = 0.f;
    for (int idx = 0; idx < deg; idx++){
      int e = order[rp+idx];
      acc += h2b[(size_t)e*128 + t];
    }
    h2s[t] = acc;
    er[t]  = emb[(size_t)Z[n]*128 + t];
  }
  __syncthreads();
  float* xp = X + (size_t)n*3712;
  for (int idx = t; idx < 3712; idx += 256){
    int k = idx >> 7, c = idx & 127;
    float acc = 0.f;
    for (int j = 0; j < 128; j++) acc += h2s[j]*Weproj[(size_t)j*3712 + idx];
    float v = acc / 23.395238876342773f;
    if (k == 0) v += er[c];
    xp[idx] = v;
  }
}

// ---------------- per-layer: rms + P projections (PV, P0, Q0) ----------------
__global__ __launch_bounds__(256) void k_pqv(
    const float* __restrict__ X, const float* __restrict__ gamma1,
    const float* __restrict__ Wmsg, const float* __restrict__ Wv,
    float* __restrict__ PVb, float* __restrict__ P0, float* __restrict__ Q0, int layer)
{
  __shared__ float ybuf[KM*128];
  __shared__ float pq[2][128];
  int n = blockIdx.x, t = threadIdx.x;
  int wid = t >> 6, lane = t & 63;
  const float* g1 = gamma1 + layer*128;
  const float* xp = X + (size_t)n*3712;
  for (int k = wid; k < KM; k += 4){
    float x0 = xp[k*128 + lane], x1 = xp[k*128 + 64 + lane];
    float ss = wave_reduce_sum(x0*x0 + x1*x1);
    float sc = rsqrtf(ss*(1.0f/128.0f) + 1e-6f);
    ybuf[k*128 + lane]      = x0*sc*g1[lane];
    ybuf[k*128 + 64 + lane] = x1*sc*g1[64+lane];
  }
  __syncthreads();
  const float* Wm  = Wmsg + (size_t)layer*16384;
  const float* Wvp = Wv   + (size_t)layer*8192;
  for (int m = 0; m < 15; m++){
    int sel = t >> 7;
    int k = 2*m + sel;
    int tt = t & 127;
    if (k < KM){
      int j = tt & 63;
      const float* wb = Wm + ((tt < 64) ? 0 : 8192) + j;
      float acc = 0.f;
      for (int c = 0; c < 128; c++) acc += ybuf[k*128 + c]*wb[c*64];
      pq[sel][tt] = acc;
    }
    __syncthreads();
    if (k < KM){
      float aPV = 0.f;
      for (int j = 0; j < 64; j++) aPV += pq[sel][j]*Wvp[j*128 + tt];
      PVb[(size_t)n*3712 + k*128 + tt] = aPV;
      if (k == 0){
        if (tt < 64) P0[(size_t)n*64 + tt]      = pq[0][tt];
        else         Q0[(size_t)n*64 + tt - 64] = pq[0][tt];
      }
    }
    __syncthreads();
  }
}

// ---------------- per-layer: edge logits ----------------
__global__ __launch_bounds__(256) void k_edge_logits(
    const int* __restrict__ EI, const float* __restrict__ P0, const float* __restrict__ Q0,
    const float* __restrict__ radl, const float* __restrict__ Wap, const float* __restrict__ wa,
    float* __restrict__ logi, int E, int layer)
{
  __shared__ float m0b[4][64];
  int wid = threadIdx.x >> 6, lane = threadIdx.x & 63;
  int e = blockIdx.x*4 + wid;
  if (e >= E) return;
  int src = EI[e], tgt = EI[E+e];
  float r0 = radl[(size_t)e*28 + layer*7];
  m0b[wid][lane] = (P0[(size_t)src*64 + lane] + Q0[(size_t)tgt*64 + lane]) * r0;
  const float* Wa = Wap + (size_t)layer*16384;
  float pa0=0,pa1=0,pa2=0,pa3=0;
  const int o4 = 4*lane;
  for (int j = 0; j < 64; j++){
    float mj = m0b[wid][j];
    const float4 w4 = *(const float4*)(Wa + j*256 + o4);
    pa0 += mj*w4.x; pa1 += mj*w4.y; pa2 += mj*w4.z; pa3 += mj*w4.w;
  }
  const float* wav = wa + layer*256;
  float lg = silu_f(pa0)*wav[o4] + silu_f(pa1)*wav[o4+1] + silu_f(pa2)*wav[o4+2] + silu_f(pa3)*wav[o4+3];
  lg += __shfl_xor(lg, 1); lg += __shfl_xor(lg, 2); lg += __shfl_xor(lg, 4);
  if ((lane & 7) == 0) logi[(size_t)e*8 + (lane >> 3)] = lg;
}

// ---------------- per-layer: softmax + gate + aggregate + QV + Wo + x add ----------------
__global__ __launch_bounds__(256) void k_attn(
    const int* __restrict__ EI, const int* __restrict__ rowptr, const int* __restrict__ order,
    const float* __restrict__ gamma1, const float* __restrict__ Wmsg,
    const float* __restrict__ Wv, const float* __restrict__ Wg, const float* __restrict__ Wo,
    const float* __restrict__ PVb, const float* __restrict__ P0, const float* __restrict__ Q0,
    const float* __restrict__ logi, const float* __restrict__ envb, const float* __restrict__ radl,
    float* __restrict__ X, int E, int layer)
{
  __shared__ float smem[KM*128];   // ybuf, then reused as aggs
  __shared__ float qm[KM*64];
  __shared__ float m0s[64*64];
  __shared__ float rl7[64*8];
  __shared__ float at_s[64*8];
  __shared__ float q0s[64];
  __shared__ float mh[8], iden[8];
  __shared__ int   srcs[64];
  int n = blockIdx.x, t = threadIdx.x;
  int rp = rowptr[n], deg = rowptr[n+1] - rp;
  if (deg == 0) return;   // uniform per block
  // A: softmax stats per head
  if (t < 8){
    float m = -3.0e38f;
    for (int idx = 0; idx < deg; idx++){ int e = order[rp+idx]; m = fmaxf(m, logi[(size_t)e*8 + t]); }
    float den = 0.f;
    for (int idx = 0; idx < deg; idx++){ int e = order[rp+idx]; den += envb[e]*__expf(logi[(size_t)e*8 + t] - m); }
    mh[t] = m; iden[t] = 1.0f/(den + 1e-16f);
  }
  // B: y = rms(x)*gamma1 into smem; Q0 row cached
  {
    int wid = t >> 6, lane = t & 63;
    const float* g1 = gamma1 + layer*128;
    const float* xp = X + (size_t)n*3712;
    for (int k = wid; k < KM; k += 4){
      float x0 = xp[k*128 + lane], x1 = xp[k*128 + 64 + lane];
      float ss = wave_reduce_sum(x0*x0 + x1*x1);
      float sc = rsqrtf(ss*(1.0f/128.0f) + 1e-6f);
      smem[k*128 + lane]      = x0*sc*g1[lane];
      smem[k*128 + 64 + lane] = x1*sc*g1[64+lane];
    }
  }
  if (t < 64) q0s[t] = Q0[(size_t)n*64 + t];
  __syncthreads();
  // C: qm[k][j] = Q-part of message projection (Wmsg rows 128..255)
  const float* Wm2 = Wmsg + (size_t)layer*16384 + 8192;
  for (int idx = t; idx < KM*64; idx += 256){
    int k = idx >> 6, j = idx & 63;
    float acc = 0.f;
    for (int c = 0; c < 128; c++) acc += smem[k*128 + c]*Wm2[c*64 + j];
    qm[idx] = acc;
  }
  __syncthreads();
  // D: edge chunks — gate recompute + PV gather
  int kg = t >> 7, hv = t & 127, h = hv >> 4;
  const float* Wgp = Wg + (size_t)layer*8192;
  float acc[15];
  #pragma unroll
  for (int j = 0; j < 15; j++) acc[j] = 0.f;
  float S[7];
  #pragma unroll
  for (int l = 0; l < 7; l++) S[l] = 0.f;
  for (int base = 0; base < deg; base += 64){
    int ne = min(64, deg - base);
    if (t < ne){
      int e = order[rp + base + t];
      srcs[t] = EI[e];
      const float* rl = radl + (size_t)e*28 + layer*7;
      #pragma unroll
      for (int l = 0; l < 7; l++) rl7[t*8 + l] = rl[l];
      float ev = envb[e];
      #pragma unroll
      for (int hh = 0; hh < 8; hh++) at_s[t*8 + hh] = ev*__expf(logi[(size_t)e*8 + hh] - mh[hh])*iden[hh];
    }
    __syncthreads();
    #pragma unroll
    for (int u = 0; u < 16; u++){
      int idx = t + u*256;
      int i = idx >> 6, j = idx & 63;
      if (i < ne) m0s[idx] = (P0[(size_t)srcs[i]*64 + j] + q0s[j]) * rl7[i*8];
    }
    __syncthreads();
    for (int i = 0; i < ne; i++){
      float g = 0.f;
      const float* mrow = m0s + i*64;
      for (int j = 0; j < 64; j++) g += mrow[j]*Wgp[j*128 + hv];
      g = silu_f(g);
      float w = g * at_s[i*8 + h];
      float rw[7];
      #pragma unroll
      for (int l = 0; l < 7; l++){ rw[l] = rl7[i*8 + l]*w; S[l] += rw[l]; }
      const float* pv = PVb + (size_t)srcs[i]*3712 + kg*128 + hv;
      #pragma unroll
      for (int j = 0; j < 15; j++){
        if (kg == 0 || j < 14){
          float s = (kg == 0) ? rw[LOFc(2*j)] : rw[LOFc(2*j+1)];
          acc[j] += pv[j*256]*s;
        }
      }
    }
    __syncthreads();
  }
  // E: add QV*S term, write aggs (reuse smem)
  const float* Wvp = Wv + (size_t)layer*8192;
  float* aggs = smem;
  #pragma unroll
  for (int j = 0; j < 15; j++){
    if (kg == 0 || j < 14){
      int k = kg + 2*j;
      float qv = 0.f;
      for (int j2 = 0; j2 < 64; j2++) qv += qm[k*64 + j2]*Wvp[j2*128 + hv];
      float s = (kg == 0) ? S[LOFc(2*j)] : S[LOFc(2*j+1)];
      acc[j] += qv*s;
      aggs[k*128 + hv] = acc[j];
    }
  }
  __syncthreads();
  // F: out = aggs @ Wo, add into X
  const float* Wop = Wo + (size_t)layer*16384;
  float* xp = X + (size_t)n*3712;
  float o[15];
  #pragma unroll
  for (int j = 0; j < 15; j++) o[j] = 0.f;
  for (int v = 0; v < 128; v++){
    float wv = Wop[v*128 + hv];
    #pragma unroll
    for (int j = 0; j < 15; j++){
      if (kg == 0 || j < 14) o[j] += aggs[(kg + 2*j)*128 + v]*wv;
    }
  }
  #pragma unroll
  for (int j = 0; j < 15; j++){
    if (kg == 0 || j < 14) xp[(kg + 2*j)*128 + hv] += o[j];
  }
}

// ---------------- per-layer: gated FFN ----------------
__global__ __launch_bounds__(256) void k_ffn(
    float* __restrict__ X, const float* __restrict__ gamma2,
    const float* __restrict__ Wfg, const float* __restrict__ Wf1, const float* __restrict__ Wf2,
    int layer)
{
  __shared__ float xs[KM*128];
  __shared__ float ys[KM*128];
  __shared__ float hs[KM*128];
  __shared__ float gf[128];
  int n = blockIdx.x, t = threadIdx.x;
  int wid = t >> 6, lane = t & 63;
  float* xp = X + (size_t)n*3712;
  for (int idx = t; idx < 3712; idx += 256) xs[idx] = xp[idx];
  __syncthreads();
  const float* g2 = gamma2 + layer*128;
  for (int k = wid; k < KM; k += 4){
    float x0 = xs[k*128 + lane], x1 = xs[k*128 + 64 + lane];
    float ss = wave_reduce_sum(x0*x0 + x1*x1);
    float sc = rsqrtf(ss*(1.0f/128.0f) + 1e-6f);
    ys[k*128 + lane]      = x0*sc*g2[lane];
    ys[k*128 + 64 + lane] = x1*sc*g2[64+lane];
  }
  __syncthreads();
  const float* Wfgp = Wfg + (size_t)layer*16384;
  if (t < 128){
    float acc = 0.f;
    for (int c = 0; c < 128; c++) acc += ys[c]*Wfgp[c*128 + t];
    gf[t] = silu_f(acc);
  }
  __syncthreads();
  const float* Wf1p = Wf1 + (size_t)layer*16384;
  for (int idx = t; idx < 3712; idx += 256){
    int k = idx >> 7, f = idx & 127;
    float acc = 0.f;
    for (int c = 0; c < 128; c++) acc += ys[k*128 + c]*Wf1p[c*128 + f];
    hs[idx] = acc*gf[f];
  }
  __syncthreads();
  const float* Wf2p = Wf2 + (size_t)layer*16384;
  for (int idx = t; idx < 3712; idx += 256){
    int k = idx >> 7, c = idx & 127;
    float acc = 0.f;
    for (int f = 0; f < 128; f++) acc += hs[k*128 + f]*Wf2p[f*128 + c];
    xp[idx] = xs[idx] + acc;
  }
}

// ---------------- output head ----------------
__global__ __launch_bounds__(256) void k_head(
    const float* __restrict__ X, const float* __restrict__ Wh1, const float* __restrict__ Wh2,
    float* __restrict__ partial, int N)
{
  __shared__ float wsum[4];
  int t = threadIdx.x;
  int half = t >> 7;
  int n = blockIdx.x*2 + half;
  int f = t & 127;
  float sv = 0.f;
  if (n < N){
    const float* xp = X + (size_t)n*3712;
    float acc = 0.f;
    for (int c = 0; c < 128; c++) acc += xp[c]*Wh1[c*128 + f];
    sv = silu_f(acc)*Wh2[f];
  }
  sv = wave_reduce_sum(sv);
  if ((t & 63) == 0) wsum[t >> 6] = sv;
  __syncthreads();
  if (t == 0) partial[blockIdx.x] = wsum[0] + wsum[1] + wsum[2] + wsum[3];
}

__global__ __launch_bounds__(256) void k_reduce(const float* __restrict__ partial, float* __restrict__ out, int P){
  __shared__ float sh[256];
  int t = threadIdx.x;
  float s = 0.f;
  for (int i = t; i < P; i += 256) s += partial[i];
  sh[t] = s; __syncthreads();
  for (int off = 128; off > 0; off >>= 1){
    if (t < off) sh[t] += sh[t+off];
    __syncthreads();
  }
  if (t == 0) out[0] = sh[0] / 77.81317f;
}

extern "C" void kernel_launch(void* const* d_in, const int* in_sizes, int n_in,
                              void* d_out, int out_size, void* d_ws, size_t ws_size,
                              hipStream_t stream)
{
  const int*   Z      = (const int*)d_in[0];
  const int*   EI     = (const int*)d_in[1];
  const float* ed     = (const float*)d_in[2];
  const float* emb    = (const float*)d_in[3];
  const float* We0    = (const float*)d_in[4];
  const float* be0    = (const float*)d_in[5];
  const float* We1    = (const float*)d_in[6];
  const float* be1    = (const float*)d_in[7];
  const float* Weproj = (const float*)d_in[8];
  const float* gamma1 = (const float*)d_in[9];
  const float* gamma2 = (const float*)d_in[10];
  const float* Wr0    = (const float*)d_in[11];
  const float* Wr1    = (const float*)d_in[12];
  const float* Wrl    = (const float*)d_in[13];
  const float* Wmsg   = (const float*)d_in[14];
  const float* Wap    = (const float*)d_in[15];
  const float* wa     = (const float*)d_in[16];
  const float* Wg     = (const float*)d_in[17];
  const float* Wv     = (const float*)d_in[18];
  const float* Wo     = (const float*)d_in[19];
  const float* Wf1    = (const float*)d_in[20];
  const float* Wfg    = (const float*)d_in[21];
  const float* Wf2    = (const float*)d_in[22];
  const float* Wh1    = (const float*)d_in[23];
  const float* Wh2    = (const float*)d_in[24];

  const int N = in_sizes[0];
  const int E = in_sizes[2];

  float* ws = (float*)d_ws;
  size_t o = 0;
  float* X    = ws + o; o += (size_t)N*3712;
  float* PVb  = ws + o; o += (size_t)N*3712;   // h2b (E*128) aliases here pre-layer-0
  float* P0   = ws + o; o += (size_t)N*64;
  float* Q0   = ws + o; o += (size_t)N*64;
  float* radl = ws + o; o += (size_t)E*28;
  float* envb = ws + o; o += (size_t)E;
  float* logi = ws + o; o += (size_t)E*8;
  float* part = ws + o; o += (size_t)((N+1)/2) + 2;
  int* rowptr = (int*)(ws + o); o += (size_t)N + 1;
  int* curs   = (int*)(ws + o); o += (size_t)N;
  int* order  = (int*)(ws + o); o += (size_t)E;
  // total ~199.5 MB for N=6000, E=120000

  float* h2b = PVb;   // alias: dead before layer 0 writes PVb

  // CSR by target
  hipMemsetAsync(curs, 0, sizeof(int)*N, stream);
  k_count<<<(E+255)/256, 256, 0, stream>>>(EI, curs, E);
  k_scan<<<1, 1024, 0, stream>>>(curs, rowptr, N);
  k_fill<<<(E+255)/256, 256, 0, stream>>>(EI, curs, order, E);
  k_sort<<<(N+255)/256, 256, 0, stream>>>(rowptr, order, N);

  // radial stage + x init
  k_edge_embed<<<(E+3)/4, 256, 0, stream>>>(ed, We0, be0, We1, be1, Wr0, Wr1, Wrl, h2b, radl, envb, E);
  k_init_x<<<N, 256, 0, stream>>>(Z, emb, Weproj, h2b, rowptr, order, X);

  for (int i = 0; i < 4; i++){
    k_pqv<<<N, 256, 0, stream>>>(X, gamma1, Wmsg, Wv, PVb, P0, Q0, i);
    k_edge_logits<<<(E+3)/4, 256, 0, stream>>>(EI, P0, Q0, radl, Wap, wa, logi, E, i);
    k_attn<<<N, 256, 0, stream>>>(EI, rowptr, order, gamma1, Wmsg, Wv, Wg, Wo,
                                  PVb, P0, Q0, logi, envb, radl, X, E, i);
    k_ffn<<<N, 256, 0, stream>>>(X, gamma2, Wfg, Wf1, Wf2, i);
  }

  int PB = (N+1)/2;
  k_head<<<PB, 256, 0, stream>>>(X, Wh1, Wh2, part, N);
  k_reduce<<<1, 256, 0, stream>>>(part, (float*)d_out, PB);
}

// Round 3
// 3236.089 us; speedup vs baseline: 4.4845x; 4.4845x over previous
//
#include <hip/hip_runtime.h>

#define KM 29
#define GTAB 4096

typedef __bf16 bf16_t;
typedef __bf16 bf16x8 __attribute__((ext_vector_type(8)));
typedef float  f32x4  __attribute__((ext_vector_type(4)));

__device__ __forceinline__ float silu_f(float x){ return x / (1.0f + __expf(-x)); }

__device__ __forceinline__ float wave_reduce_sum(float v){
  #pragma unroll
  for (int s = 1; s < 64; s <<= 1) v += __shfl_xor(v, s);
  return v;
}

__device__ __forceinline__ constexpr int LOFc(int k){
  return (k==0)?0 : (k<4)?1 : (k<9)?2 : (k<14)?3 : (k<19)?4 : (k<24)?5 : 6;
}

__device__ __forceinline__ f32x4 mfma16(bf16x8 a, bf16x8 b, f32x4 c){
  return __builtin_amdgcn_mfma_f32_16x16x32_bf16(a, b, c, 0, 0, 0);
}

// ---------------- CSR build ----------------
__global__ void k_count(const int* __restrict__ EI, int* __restrict__ cnt, int E){
  int e = blockIdx.x*256 + threadIdx.x;
  if (e < E) atomicAdd(&cnt[EI[E+e]], 1);
}

__global__ __launch_bounds__(1024) void k_scan(int* __restrict__ cnt, int* __restrict__ rowptr, int N){
  __shared__ int ts[1024];
  int t = threadIdx.x;
  int base = t*8;
  int loc[8]; int sum = 0;
  #pragma unroll
  for (int u = 0; u < 8; u++){ int idx = base+u; int v = (idx < N) ? cnt[idx] : 0; loc[u] = sum; sum += v; }
  ts[t] = sum; __syncthreads();
  for (int off = 1; off < 1024; off <<= 1){
    int v = (t >= off) ? ts[t-off] : 0;
    __syncthreads();
    ts[t] += v;
    __syncthreads();
  }
  int excl = ts[t] - sum;
  #pragma unroll
  for (int u = 0; u < 8; u++){
    int idx = base+u;
    if (idx < N){ int r = excl + loc[u]; rowptr[idx] = r; cnt[idx] = r; }
  }
  if (t == 1023) rowptr[N] = ts[1023];
}

__global__ void k_fill(const int* __restrict__ EI, int* __restrict__ cur, int* __restrict__ order, int E){
  int e = blockIdx.x*256 + threadIdx.x;
  if (e < E){ int pos = atomicAdd(&cur[EI[E+e]], 1); order[pos] = e; }
}

__global__ void k_sort(const int* __restrict__ rowptr, int* __restrict__ order, int N){
  int n = blockIdx.x*256 + threadIdx.x;
  if (n >= N) return;
  int rp = rowptr[n], re = rowptr[n+1];
  for (int a = rp+1; a < re; a++){
    int key = order[a]; int b = a-1;
    while (b >= rp && order[b] > key){ order[b+1] = order[b]; b--; }
    order[b+1] = key;
  }
}

// ---------------- weight transpose to bf16 arena ----------------
// dst[(l*C + c)*R + r] = src[l*Lstr + r*C + c]
__global__ void k_tr(const float* __restrict__ src, bf16_t* __restrict__ dst,
                     int L, int R, int C, int Lstr){
  int idx = blockIdx.x*256 + threadIdx.x;
  int total = L*R*C;
  if (idx >= total) return;
  int l = idx / (R*C); int rem = idx - l*(R*C);
  int r = rem / C; int c = rem - r*C;
  dst[((size_t)l*C + c)*R + r] = (bf16_t)src[(size_t)l*Lstr + (size_t)r*C + c];
}

// ---------------- radial MLP table build (4096 grid points) ----------------
__global__ __launch_bounds__(256) void k_tab_embed(
    const float* __restrict__ We0, const float* __restrict__ be0,
    const float* __restrict__ We1, const float* __restrict__ be1,
    const float* __restrict__ Wr0, const float* __restrict__ Wr1, const float* __restrict__ Wrl,
    float* __restrict__ h2tab, float* __restrict__ radtab)
{
  __shared__ float sb[4][640];
  const int wid = threadIdx.x >> 6, lane = threadIdx.x & 63;
  const int e = blockIdx.x*4 + wid;
  if (e >= GTAB) return;
  const float d = e * (12.0f/(GTAB-1));
  const float DLT = 12.0f/599.0f;
  const float CO  = -0.5f/((2.0f*DLT)*(2.0f*DLT));
  int jc = (int)(d/DLT + 0.5f);
  int j0 = jc - 16; if (j0 < 0) j0 = 0; if (j0 > 600-32) j0 = 600-32;
  float diff = d - (float)(j0+lane)*DLT;   // lanes >=32 unused
  float gval = __expf(CO*diff*diff);
  float p[10];
  #pragma unroll
  for (int u = 0; u < 10; u++) p[u] = 0.f;
  const int c2 = 2*lane;
  for (int jj = 0; jj < 32; jj++){
    float gj = __shfl(gval, jj);
    int row = j0 + jj;
    const float2 w0 = *(const float2*)(We0 + row*128 + c2);
    p[0] += gj*w0.x; p[1] += gj*w0.y;
    #pragma unroll
    for (int i = 0; i < 4; i++){
      const float2 wr = *(const float2*)(Wr0 + ((size_t)i*600 + row)*128 + c2);
      p[2+2*i] += gj*wr.x; p[3+2*i] += gj*wr.y;
    }
  }
  sb[wid][c2]   = silu_f(p[0] + be0[c2]);
  sb[wid][c2+1] = silu_f(p[1] + be0[c2+1]);
  #pragma unroll
  for (int i = 0; i < 4; i++){
    sb[wid][128 + 128*i + c2]   = silu_f(p[2+2*i]);
    sb[wid][128 + 128*i + c2+1] = silu_f(p[3+2*i]);
  }
  float a0 = 0.f, a1 = 0.f;
  for (int c = 0; c < 128; c++){
    float hv = sb[wid][c];
    const float2 w = *(const float2*)(We1 + c*128 + c2);
    a0 += hv*w.x; a1 += hv*w.y;
  }
  a0 = silu_f(a0 + be1[c2]); a1 = silu_f(a1 + be1[c2+1]);
  h2tab[(size_t)e*128 + c2]     = a0;
  h2tab[(size_t)e*128 + c2 + 1] = a1;
  #pragma unroll
  for (int i = 0; i < 4; i++){
    float r0 = 0.f, r1 = 0.f;
    const float* W1 = Wr1 + (size_t)i*128*128;
    for (int c = 0; c < 128; c++){
      float rv = sb[wid][128 + 128*i + c];
      const float2 w = *(const float2*)(W1 + c*128 + c2);
      r0 += rv*w.x; r1 += rv*w.y;
    }
    r0 = silu_f(r0); r1 = silu_f(r1);
    const float* Wl = Wrl + (size_t)i*128*7;
    float pl[7];
    #pragma unroll
    for (int l = 0; l < 7; l++) pl[l] = r0*Wl[c2*7+l] + r1*Wl[(c2+1)*7+l];
    #pragma unroll
    for (int l = 0; l < 7; l++) pl[l] = wave_reduce_sum(pl[l]);
    if (lane == 0){
      #pragma unroll
      for (int l = 0; l < 7; l++) radtab[(size_t)e*28 + i*7 + l] = pl[l];
    }
  }
}

// ---------------- per-edge radl + env via table interp ----------------
__global__ void k_radinterp(const float* __restrict__ ed, const float* __restrict__ radtab,
                            float* __restrict__ radl, float* __restrict__ envb, int E){
  int e = blockIdx.x*256 + threadIdx.x;
  if (e >= E) return;
  float d = ed[e];
  float u = d * ((GTAB-1)/12.0f);
  int j = (int)u; if (j > GTAB-2) j = GTAB-2;
  float f = u - (float)j;
  const float* t0 = radtab + (size_t)j*28;
  for (int q = 0; q < 28; q++){
    float a = t0[q], b = t0[28+q];
    radl[(size_t)e*28+q] = a + f*(b-a);
  }
  float xx = d*(1.0f/12.0f);
  float x2=xx*xx, x4=x2*x2, x5=x4*xx;
  float env = 1.0f - 21.0f*x5 + 35.0f*x5*xx - 15.0f*x5*x2;
  envb[e] = (xx<1.0f)?env:0.0f;
}

// ---------------- x init: h2 sums (interp) + MFMA Weproj ----------------
__global__ __launch_bounds__(256) void k_init_x(
    const int* __restrict__ Z, const float* __restrict__ ed, const float* __restrict__ emb,
    const bf16_t* __restrict__ WeprojT, const float* __restrict__ h2tab,
    const int* __restrict__ rowptr, const int* __restrict__ order,
    float* __restrict__ X, int N)
{
  __shared__ bf16_t h2s[32*136];
  __shared__ int Zs[32];
  int n0 = blockIdx.x*32, t = threadIdx.x;
  int half = t >> 7, ch = t & 127;
  for (int pair = 0; pair < 16; pair++){
    int nn = pair*2 + half;
    int n = n0 + nn;
    float acc = 0.f;
    if (n < N){
      int rp = rowptr[n], deg = rowptr[n+1]-rp;
      for (int idx = 0; idx < deg; idx++){
        int e = order[rp+idx];
        float d = ed[e];
        float u = d * ((GTAB-1)/12.0f);
        int j = (int)u; if (j > GTAB-2) j = GTAB-2;
        float f = u - (float)j;
        float a = h2tab[(size_t)j*128 + ch], b = h2tab[(size_t)(j+1)*128 + ch];
        acc += a + f*(b-a);
      }
    }
    h2s[nn*136 + ch] = (bf16_t)acc;
  }
  if (t < 32) Zs[t] = (n0 + t < N) ? Z[n0+t] : 0;
  __syncthreads();
  int wid = t >> 6, lane = t & 63;
  int mtile = wid & 1;
  int row = mtile*16 + (lane & 15);
  int koff = (lane >> 4)*8;
  bf16x8 afr[4];
  #pragma unroll
  for (int kk = 0; kk < 4; kk++) afr[kk] = *(const bf16x8*)(h2s + row*136 + kk*32 + koff);
  for (int nt = (wid>>1); nt < 232; nt += 2){
    f32x4 acc = {0.f,0.f,0.f,0.f};
    int col = nt*16 + (lane & 15);
    #pragma unroll
    for (int kk = 0; kk < 4; kk++){
      bf16x8 b = *(const bf16x8*)(WeprojT + (size_t)col*128 + kk*32 + koff);
      acc = mfma16(afr[kk], b, acc);
    }
    #pragma unroll
    for (int r = 0; r < 4; r++){
      int r32 = mtile*16 + (lane>>4)*4 + r;
      int n = n0 + r32;
      if (n < N){
        float v = acc[r] * (1.0f/23.395238876342773f);
        if (col < 128) v += emb[(size_t)Zs[r32]*128 + col];
        X[(size_t)n*3712 + col] = v;
      }
    }
  }
}

// ---------------- per-layer: rms + P0/Q0 + P -> PV (MFMA) ----------------
__global__ __launch_bounds__(256) void k_pqv(
    const float* __restrict__ X, const float* __restrict__ gamma1,
    const float* __restrict__ Wmsg, const bf16_t* __restrict__ WmsgPT, const bf16_t* __restrict__ WvT,
    bf16_t* __restrict__ PVb, float* __restrict__ P0, float* __restrict__ Q0, int layer)
{
  __shared__ bf16_t ys16[32*136];
  __shared__ bf16_t ps16[32*72];
  int n = blockIdx.x, t = threadIdx.x;
  int wid = t >> 6, lane = t & 63;
  const float* g1 = gamma1 + layer*128;
  const float* xp = X + (size_t)n*3712;
  for (int k = wid; k < KM; k += 4){
    float x0 = xp[k*128 + lane], x1 = xp[k*128 + 64 + lane];
    float ss = wave_reduce_sum(x0*x0 + x1*x1);
    float sc = rsqrtf(ss*(1.0f/128.0f) + 1e-6f);
    ys16[k*136 + lane]      = (bf16_t)(x0*sc*g1[lane]);
    ys16[k*136 + 64 + lane] = (bf16_t)(x1*sc*g1[64+lane]);
  }
  __syncthreads();
  // P0/Q0 (row k=0) via VALU from ys16
  const float* Wm = Wmsg + (size_t)layer*16384;
  if (t < 128){
    float acc = 0.f;
    if (t < 64){
      for (int c = 0; c < 128; c++) acc += (float)ys16[c] * Wm[(128+c)*64 + t];
      Q0[(size_t)n*64 + t] = acc;
    } else {
      int tt = t - 64;
      for (int c = 0; c < 128; c++) acc += (float)ys16[c] * Wm[c*64 + tt];
      P0[(size_t)n*64 + tt] = acc;
    }
  }
  // GEMM1: P[32x64] = ys16 @ WmsgPT
  {
    const bf16_t* Bt = WmsgPT + (size_t)layer*8192;
    int mtile = wid >> 1;
    int row = mtile*16 + (lane & 15);
    int koff = (lane >> 4)*8;
    f32x4 acc[2] = {{0,0,0,0},{0,0,0,0}};
    #pragma unroll
    for (int kk = 0; kk < 128; kk += 32){
      bf16x8 a = *(const bf16x8*)(ys16 + row*136 + kk + koff);
      #pragma unroll
      for (int u = 0; u < 2; u++){
        int col = ((wid&1)*2+u)*16 + (lane & 15);
        bf16x8 b = *(const bf16x8*)(Bt + (size_t)col*128 + kk + koff);
        acc[u] = mfma16(a, b, acc[u]);
      }
    }
    #pragma unroll
    for (int u = 0; u < 2; u++){
      int col = ((wid&1)*2+u)*16 + (lane & 15);
      #pragma unroll
      for (int r = 0; r < 4; r++){
        int r32 = mtile*16 + (lane>>4)*4 + r;
        ps16[r32*72 + col] = (bf16_t)acc[u][r];
      }
    }
  }
  __syncthreads();
  // GEMM2: PV[32x128] = ps16 @ WvT  (K=64)
  {
    const bf16_t* Bt = WvT + (size_t)layer*8192;
    int mtile = wid >> 1;
    int nt0 = (wid & 1)*4;
    int row = mtile*16 + (lane & 15);
    int koff = (lane >> 4)*8;
    f32x4 acc[4] = {{0,0,0,0},{0,0,0,0},{0,0,0,0},{0,0,0,0}};
    #pragma unroll
    for (int kk = 0; kk < 64; kk += 32){
      bf16x8 a = *(const bf16x8*)(ps16 + row*72 + kk + koff);
      #pragma unroll
      for (int u = 0; u < 4; u++){
        int col = (nt0+u)*16 + (lane & 15);
        bf16x8 b = *(const bf16x8*)(Bt + (size_t)col*64 + kk + koff);
        acc[u] = mfma16(a, b, acc[u]);
      }
    }
    bf16_t* pvp = PVb + (size_t)n*3712;
    #pragma unroll
    for (int u = 0; u < 4; u++){
      int col = (nt0+u)*16 + (lane & 15);
      #pragma unroll
      for (int r = 0; r < 4; r++){
        int r32 = mtile*16 + (lane>>4)*4 + r;
        if (r32 < KM) pvp[r32*128 + col] = (bf16_t)acc[u][r];
      }
    }
  }
}

// ---------------- per-layer: edge logits + gate (4 edges/wave) ----------------
__global__ __launch_bounds__(256) void k_edge_logits(
    const int* __restrict__ EI, const float* __restrict__ P0, const float* __restrict__ Q0,
    const float* __restrict__ radl, const float* __restrict__ Wap, const float* __restrict__ wa,
    const float* __restrict__ Wg, float* __restrict__ logi, bf16_t* __restrict__ gate16,
    int E, int layer)
{
  __shared__ float m0s[16*64];
  __shared__ int   srcs[16], tgts[16];
  __shared__ float r0s[16];
  int t = threadIdx.x;
  int eb = blockIdx.x*16;
  if (t < 16){
    int e = eb + t;
    if (e < E){
      srcs[t] = EI[e]; tgts[t] = EI[E+e];
      r0s[t] = radl[(size_t)e*28 + layer*7];
    }
  }
  __syncthreads();
  #pragma unroll
  for (int u = 0; u < 4; u++){
    int idx = t + u*256;
    int i = idx >> 6, j = idx & 63;
    if (eb + i < E) m0s[idx] = (P0[(size_t)srcs[i]*64 + j] + Q0[(size_t)tgts[i]*64 + j]) * r0s[i];
  }
  __syncthreads();
  int wid = t >> 6, lane = t & 63;
  const float* Wa  = Wap + (size_t)layer*16384;
  const float* Wgp = Wg  + (size_t)layer*8192;
  const int o4 = 4*lane, c2 = 2*lane;
  float pa[4][4] = {};
  float gg[4][2] = {};
  for (int j = 0; j < 64; j++){
    const float4 w4  = *(const float4*)(Wa + j*256 + o4);
    const float2 wg2 = *(const float2*)(Wgp + j*128 + c2);
    #pragma unroll
    for (int q = 0; q < 4; q++){
      float mj = m0s[(wid*4+q)*64 + j];
      pa[q][0] += mj*w4.x; pa[q][1] += mj*w4.y; pa[q][2] += mj*w4.z; pa[q][3] += mj*w4.w;
      gg[q][0] += mj*wg2.x; gg[q][1] += mj*wg2.y;
    }
  }
  const float* wav = wa + layer*256;
  float wa0 = wav[o4], wa1 = wav[o4+1], wa2 = wav[o4+2], wa3 = wav[o4+3];
  #pragma unroll
  for (int q = 0; q < 4; q++){
    int e = eb + wid*4 + q;
    if (e >= E) continue;
    gate16[(size_t)e*128 + c2]     = (bf16_t)silu_f(gg[q][0]);
    gate16[(size_t)e*128 + c2 + 1] = (bf16_t)silu_f(gg[q][1]);
    float lg = silu_f(pa[q][0])*wa0 + silu_f(pa[q][1])*wa1 + silu_f(pa[q][2])*wa2 + silu_f(pa[q][3])*wa3;
    lg += __shfl_xor(lg, 1); lg += __shfl_xor(lg, 2); lg += __shfl_xor(lg, 4);
    if ((lane & 7) == 0) logi[(size_t)e*8 + (lane >> 3)] = lg;
  }
}

// ---------------- per-layer: softmax + gather + QV + Wo (MFMA) + x add ----------------
__global__ __launch_bounds__(256) void k_attn(
    const int* __restrict__ EI, const int* __restrict__ rowptr, const int* __restrict__ order,
    float* __restrict__ X, const float* __restrict__ gamma1,
    const bf16_t* __restrict__ WmsgQT, const bf16_t* __restrict__ WvT, const bf16_t* __restrict__ WoT,
    const bf16_t* __restrict__ PVb, const bf16_t* __restrict__ gate16,
    const float* __restrict__ logi, const float* __restrict__ envb, const float* __restrict__ radl,
    int layer)
{
  __shared__ bf16_t ys16[32*136];     // reused as ag16 after gather
  __shared__ bf16_t qs16[32*72];
  __shared__ bf16_t qvs16[KM*128];
  __shared__ float rl7[64*8];
  __shared__ float at8[64*8];
  __shared__ int   srcs[64], es[64];
  __shared__ float mh[8], iden[8];
  int n = blockIdx.x, t = threadIdx.x;
  int rp = rowptr[n], deg = rowptr[n+1]-rp;
  if (deg == 0) return;
  if (t < 8){
    float m = -3.0e38f;
    for (int idx = 0; idx < deg; idx++){ int e = order[rp+idx]; m = fmaxf(m, logi[(size_t)e*8 + t]); }
    float den = 0.f;
    for (int idx = 0; idx < deg; idx++){ int e = order[rp+idx]; den += envb[e]*__expf(logi[(size_t)e*8 + t] - m); }
    mh[t] = m; iden[t] = 1.0f/(den + 1e-16f);
  }
  int wid = t >> 6, lane = t & 63;
  {
    const float* g1 = gamma1 + layer*128;
    const float* xp = X + (size_t)n*3712;
    for (int k = wid; k < KM; k += 4){
      float x0 = xp[k*128+lane], x1 = xp[k*128+64+lane];
      float ss = wave_reduce_sum(x0*x0+x1*x1);
      float sc = rsqrtf(ss*(1.0f/128.0f)+1e-6f);
      ys16[k*136+lane]    = (bf16_t)(x0*sc*g1[lane]);
      ys16[k*136+64+lane] = (bf16_t)(x1*sc*g1[64+lane]);
    }
  }
  __syncthreads();
  // qm[32x64] = ys16 @ WmsgQT
  {
    const bf16_t* Bt = WmsgQT + (size_t)layer*8192;
    int mtile = wid >> 1;
    int row = mtile*16 + (lane&15);
    int koff = (lane>>4)*8;
    f32x4 acc[2] = {{0,0,0,0},{0,0,0,0}};
    #pragma unroll
    for (int kk = 0; kk < 128; kk += 32){
      bf16x8 a = *(const bf16x8*)(ys16 + row*136 + kk + koff);
      #pragma unroll
      for (int u = 0; u < 2; u++){
        int col = ((wid&1)*2+u)*16 + (lane&15);
        bf16x8 b = *(const bf16x8*)(Bt + (size_t)col*128 + kk + koff);
        acc[u] = mfma16(a, b, acc[u]);
      }
    }
    #pragma unroll
    for (int u = 0; u < 2; u++){
      int col = ((wid&1)*2+u)*16 + (lane&15);
      #pragma unroll
      for (int r = 0; r < 4; r++){
        int r32 = mtile*16 + (lane>>4)*4 + r;
        qs16[r32*72 + col] = (bf16_t)acc[u][r];
      }
    }
  }
  __syncthreads();
  // QV[32x128] = qs16 @ WvT (K=64)
  {
    const bf16_t* Bt = WvT + (size_t)layer*8192;
    int mtile = wid >> 1;
    int nt0 = (wid&1)*4;
    int row = mtile*16 + (lane&15);
    int koff = (lane>>4)*8;
    f32x4 acc[4] = {{0,0,0,0},{0,0,0,0},{0,0,0,0},{0,0,0,0}};
    #pragma unroll
    for (int kk = 0; kk < 64; kk += 32){
      bf16x8 a = *(const bf16x8*)(qs16 + row*72 + kk + koff);
      #pragma unroll
      for (int u = 0; u < 4; u++){
        int col = (nt0+u)*16 + (lane&15);
        bf16x8 b = *(const bf16x8*)(Bt + (size_t)col*64 + kk + koff);
        acc[u] = mfma16(a, b, acc[u]);
      }
    }
    #pragma unroll
    for (int u = 0; u < 4; u++){
      int col = (nt0+u)*16 + (lane&15);
      #pragma unroll
      for (int r = 0; r < 4; r++){
        int r32 = mtile*16 + (lane>>4)*4 + r;
        if (r32 < KM) qvs16[r32*128 + col] = (bf16_t)acc[u][r];
      }
    }
  }
  // gather over edges
  int kg = t >> 7, hv = t & 127, h = hv >> 4;
  float acc[15];
  #pragma unroll
  for (int j = 0; j < 15; j++) acc[j] = 0.f;
  float S[7];
  #pragma unroll
  for (int l = 0; l < 7; l++) S[l] = 0.f;
  for (int base = 0; base < deg; base += 64){
    int ne = min(64, deg - base);
    __syncthreads();
    if (t < ne){
      int e = order[rp + base + t];
      es[t] = e; srcs[t] = EI[e];
      const float* rl = radl + (size_t)e*28 + layer*7;
      #pragma unroll
      for (int l = 0; l < 7; l++) rl7[t*8+l] = rl[l];
      float ev = envb[e];
      #pragma unroll
      for (int hh = 0; hh < 8; hh++) at8[t*8+hh] = ev*__expf(logi[(size_t)e*8+hh]-mh[hh])*iden[hh];
    }
    __syncthreads();
    for (int i = 0; i < ne; i++){
      float w = (float)gate16[(size_t)es[i]*128 + hv] * at8[i*8+h];
      float rw[7];
      #pragma unroll
      for (int l = 0; l < 7; l++){ rw[l] = rl7[i*8+l]*w; S[l] += rw[l]; }
      const bf16_t* pv = PVb + (size_t)srcs[i]*3712 + kg*128 + hv;
      #pragma unroll
      for (int j = 0; j < 15; j++){
        if (kg == 0 || j < 14){
          float s = (kg==0)? rw[LOFc(2*j)] : rw[LOFc(2*j+1)];
          acc[j] += (float)pv[j*256]*s;
        }
      }
    }
  }
  // QV*S add, write agg (bf16, alias ys16)
  bf16_t* ag16 = ys16;
  #pragma unroll
  for (int j = 0; j < 15; j++){
    if (kg == 0 || j < 14){
      int k = kg + 2*j;
      float qv = (float)qvs16[k*128 + hv];
      float s = (kg==0)? S[LOFc(2*j)] : S[LOFc(2*j+1)];
      ag16[k*136 + hv] = (bf16_t)(acc[j] + qv*s);
    }
  }
  __syncthreads();
  // out = ag16 @ WoT, += X
  {
    const bf16_t* Bt = WoT + (size_t)layer*16384;
    int mtile = wid >> 1;
    int nt0 = (wid&1)*4;
    int row = mtile*16 + (lane&15);
    int koff = (lane>>4)*8;
    f32x4 acc2[4] = {{0,0,0,0},{0,0,0,0},{0,0,0,0},{0,0,0,0}};
    #pragma unroll
    for (int kk = 0; kk < 128; kk += 32){
      bf16x8 a = *(const bf16x8*)(ag16 + row*136 + kk + koff);
      #pragma unroll
      for (int u = 0; u < 4; u++){
        int col = (nt0+u)*16 + (lane&15);
        bf16x8 b = *(const bf16x8*)(Bt + (size_t)col*128 + kk + koff);
        acc2[u] = mfma16(a, b, acc2[u]);
      }
    }
    float* xp = X + (size_t)n*3712;
    #pragma unroll
    for (int u = 0; u < 4; u++){
      int col = (nt0+u)*16 + (lane&15);
      #pragma unroll
      for (int r = 0; r < 4; r++){
        int r32 = mtile*16 + (lane>>4)*4 + r;
        if (r32 < KM) xp[r32*128 + col] += acc2[u][r];
      }
    }
  }
}

// ---------------- per-layer: gated FFN (MFMA) ----------------
__global__ __launch_bounds__(256) void k_ffn(
    float* __restrict__ X, const float* __restrict__ gamma2, const float* __restrict__ Wfg,
    const bf16_t* __restrict__ Wf1T, const bf16_t* __restrict__ Wf2T, int layer)
{
  __shared__ bf16_t ys16[32*136];
  __shared__ bf16_t hs16[32*136];
  __shared__ float gf[128];
  int n = blockIdx.x, t = threadIdx.x;
  int wid = t >> 6, lane = t & 63;
  float* xp = X + (size_t)n*3712;
  const float* g2 = gamma2 + layer*128;
  for (int k = wid; k < KM; k += 4){
    float x0 = xp[k*128+lane], x1 = xp[k*128+64+lane];
    float ss = wave_reduce_sum(x0*x0+x1*x1);
    float sc = rsqrtf(ss*(1.0f/128.0f)+1e-6f);
    ys16[k*136+lane]    = (bf16_t)(x0*sc*g2[lane]);
    ys16[k*136+64+lane] = (bf16_t)(x1*sc*g2[64+lane]);
  }
  __syncthreads();
  const float* Wfgp = Wfg + (size_t)layer*16384;
  if (t < 128){
    float acc = 0.f;
    for (int c = 0; c < 128; c++) acc += (float)ys16[c]*Wfgp[c*128 + t];
    gf[t] = silu_f(acc);
  }
  __syncthreads();
  int mtile = wid >> 1;
  int nt0 = (wid&1)*4;
  int row = mtile*16 + (lane&15);
  int koff = (lane>>4)*8;
  {
    const bf16_t* Bt = Wf1T + (size_t)layer*16384;
    f32x4 acc[4] = {{0,0,0,0},{0,0,0,0},{0,0,0,0},{0,0,0,0}};
    #pragma unroll
    for (int kk = 0; kk < 128; kk += 32){
      bf16x8 a = *(const bf16x8*)(ys16 + row*136 + kk + koff);
      #pragma unroll
      for (int u = 0; u < 4; u++){
        int col = (nt0+u)*16 + (lane&15);
        bf16x8 b = *(const bf16x8*)(Bt + (size_t)col*128 + kk + koff);
        acc[u] = mfma16(a, b, acc[u]);
      }
    }
    #pragma unroll
    for (int u = 0; u < 4; u++){
      int col = (nt0+u)*16 + (lane&15);
      float gfc = gf[col];
      #pragma unroll
      for (int r = 0; r < 4; r++){
        int r32 = mtile*16 + (lane>>4)*4 + r;
        hs16[r32*136 + col] = (bf16_t)(acc[u][r]*gfc);
      }
    }
  }
  __syncthreads();
  {
    const bf16_t* Bt = Wf2T + (size_t)layer*16384;
    f32x4 acc[4] = {{0,0,0,0},{0,0,0,0},{0,0,0,0},{0,0,0,0}};
    #pragma unroll
    for (int kk = 0; kk < 128; kk += 32){
      bf16x8 a = *(const bf16x8*)(hs16 + row*136 + kk + koff);
      #pragma unroll
      for (int u = 0; u < 4; u++){
        int col = (nt0+u)*16 + (lane&15);
        bf16x8 b = *(const bf16x8*)(Bt + (size_t)col*128 + kk + koff);
        acc[u] = mfma16(a, b, acc[u]);
      }
    }
    #pragma unroll
    for (int u = 0; u < 4; u++){
      int col = (nt0+u)*16 + (lane&15);
      #pragma unroll
      for (int r = 0; r < 4; r++){
        int r32 = mtile*16 + (lane>>4)*4 + r;
        if (r32 < KM) xp[r32*128 + col] += acc[u][r];
      }
    }
  }
}

// ---------------- output head ----------------
__global__ __launch_bounds__(256) void k_head(
    const float* __restrict__ X, const float* __restrict__ Wh1, const float* __restrict__ Wh2,
    float* __restrict__ partial, int N)
{
  __shared__ float wsum[4];
  int t = threadIdx.x;
  int half = t >> 7;
  int n = blockIdx.x*2 + half;
  int f = t & 127;
  float sv = 0.f;
  if (n < N){
    const float* xp = X + (size_t)n*3712;
    float acc = 0.f;
    for (int c = 0; c < 128; c++) acc += xp[c]*Wh1[c*128 + f];
    sv = silu_f(acc)*Wh2[f];
  }
  sv = wave_reduce_sum(sv);
  if ((t & 63) == 0) wsum[t >> 6] = sv;
  __syncthreads();
  if (t == 0) partial[blockIdx.x] = wsum[0] + wsum[1] + wsum[2] + wsum[3];
}

__global__ __launch_bounds__(256) void k_reduce(const float* __restrict__ partial, float* __restrict__ out, int P){
  __shared__ float sh[256];
  int t = threadIdx.x;
  float s = 0.f;
  for (int i = t; i < P; i += 256) s += partial[i];
  sh[t] = s; __syncthreads();
  for (int off = 128; off > 0; off >>= 1){
    if (t < off) sh[t] += sh[t+off];
    __syncthreads();
  }
  if (t == 0) out[0] = sh[0] / 77.81317f;
}

extern "C" void kernel_launch(void* const* d_in, const int* in_sizes, int n_in,
                              void* d_out, int out_size, void* d_ws, size_t ws_size,
                              hipStream_t stream)
{
  const int*   Z      = (const int*)d_in[0];
  const int*   EI     = (const int*)d_in[1];
  const float* ed     = (const float*)d_in[2];
  const float* emb    = (const float*)d_in[3];
  const float* We0    = (const float*)d_in[4];
  const float* be0    = (const float*)d_in[5];
  const float* We1    = (const float*)d_in[6];
  const float* be1    = (const float*)d_in[7];
  const float* Weproj = (const float*)d_in[8];
  const float* gamma1 = (const float*)d_in[9];
  const float* gamma2 = (const float*)d_in[10];
  const float* Wr0    = (const float*)d_in[11];
  const float* Wr1    = (const float*)d_in[12];
  const float* Wrl    = (const float*)d_in[13];
  const float* Wmsg   = (const float*)d_in[14];
  const float* Wap    = (const float*)d_in[15];
  const float* wa     = (const float*)d_in[16];
  const float* Wg     = (const float*)d_in[17];
  const float* Wv     = (const float*)d_in[18];
  const float* Wo     = (const float*)d_in[19];
  const float* Wf1    = (const float*)d_in[20];
  const float* Wfg    = (const float*)d_in[21];
  const float* Wf2    = (const float*)d_in[22];
  const float* Wh1    = (const float*)d_in[23];
  const float* Wh2    = (const float*)d_in[24];

  const int N = in_sizes[0];
  const int E = in_sizes[2];

  float* ws = (float*)d_ws;
  size_t o = 0;
  auto alloc = [&](size_t nf){ float* p = ws + o; o += (nf + 7) & ~(size_t)7; return p; };

  float* X      = alloc((size_t)N*3712);
  float* P0     = alloc((size_t)N*64);
  float* Q0     = alloc((size_t)N*64);
  float* radl   = alloc((size_t)E*28);
  float* envb   = alloc((size_t)E);
  float* logi   = alloc((size_t)E*8);
  float* part   = alloc((size_t)((N+1)/2) + 8);
  float* h2tab  = alloc((size_t)GTAB*128);
  float* radtab = alloc((size_t)GTAB*28);
  bf16_t* PVb   = (bf16_t*)alloc((size_t)N*1856);      // N*3712 bf16
  bf16_t* gate16= (bf16_t*)alloc((size_t)E*64);        // E*128 bf16
  bf16_t* arena = (bf16_t*)alloc(385024);              // 770048 bf16
  int* rowptr = (int*)alloc((size_t)N+8);
  int* curs   = (int*)alloc((size_t)N);
  int* order  = (int*)alloc((size_t)E);

  bf16_t* WmsgPT  = arena;            // [4][64][128]
  bf16_t* WmsgQT  = arena + 32768;    // [4][64][128]
  bf16_t* WvT     = arena + 65536;    // [4][128][64]
  bf16_t* WoT     = arena + 98304;    // [4][128][128]
  bf16_t* Wf1T    = arena + 163840;
  bf16_t* Wf2T    = arena + 229376;
  bf16_t* WeprojT = arena + 294912;   // [3712][128]

  // CSR by target
  hipMemsetAsync(curs, 0, sizeof(int)*N, stream);
  k_count<<<(E+255)/256, 256, 0, stream>>>(EI, curs, E);
  k_scan<<<1, 1024, 0, stream>>>(curs, rowptr, N);
  k_fill<<<(E+255)/256, 256, 0, stream>>>(EI, curs, order, E);
  k_sort<<<(N+255)/256, 256, 0, stream>>>(rowptr, order, N);

  // weight transposes -> bf16 arenas
  k_tr<<<128, 256, 0, stream>>>(Wmsg,        WmsgPT, 4, 128, 64, 16384);
  k_tr<<<128, 256, 0, stream>>>(Wmsg + 8192, WmsgQT, 4, 128, 64, 16384);
  k_tr<<<128, 256, 0, stream>>>(Wv,          WvT,    4, 64, 128, 8192);
  k_tr<<<256, 256, 0, stream>>>(Wo,          WoT,    4, 128, 128, 16384);
  k_tr<<<256, 256, 0, stream>>>(Wf1,         Wf1T,   4, 128, 128, 16384);
  k_tr<<<256, 256, 0, stream>>>(Wf2,         Wf2T,   4, 128, 128, 16384);
  k_tr<<<1856, 256, 0, stream>>>(Weproj,     WeprojT, 1, 128, 3712, 0);

  // radial tables + per-edge interp
  k_tab_embed<<<GTAB/4, 256, 0, stream>>>(We0, be0, We1, be1, Wr0, Wr1, Wrl, h2tab, radtab);
  k_radinterp<<<(E+255)/256, 256, 0, stream>>>(ed, radtab, radl, envb, E);

  // x init
  k_init_x<<<(N+31)/32, 256, 0, stream>>>(Z, ed, emb, WeprojT, h2tab, rowptr, order, X, N);

  for (int i = 0; i < 4; i++){
    k_pqv<<<N, 256, 0, stream>>>(X, gamma1, Wmsg, WmsgPT, WvT, PVb, P0, Q0, i);
    k_edge_logits<<<(E+15)/16, 256, 0, stream>>>(EI, P0, Q0, radl, Wap, wa, Wg, logi, gate16, E, i);
    k_attn<<<N, 256, 0, stream>>>(EI, rowptr, order, X, gamma1, WmsgQT, WvT, WoT,
                                  PVb, gate16, logi, envb, radl, i);
    k_ffn<<<N, 256, 0, stream>>>(X, gamma2, Wfg, Wf1T, Wf2T, i);
  }

  int PB = (N+1)/2;
  k_head<<<PB, 256, 0, stream>>>(X, Wh1, Wh2, part, N);
  k_reduce<<<1, 256, 0, stream>>>(part, (float*)d_out, PB);
}